// Round 2
// baseline (489.131 us; speedup 1.0000x reference)
//
#include <hip/hip_runtime.h>

typedef unsigned short u16;
typedef unsigned int u32;

#define NC 50000
#define NN 10000
#define NG 20000
#define NE 100000

// ---------- bf16 helpers ----------
__device__ __forceinline__ float bf1(u16 a) { return __uint_as_float(((u32)a) << 16); }
__device__ __forceinline__ u16 fbf(float f) {
  u32 u = __float_as_uint(f);
  return (u16)((u + 0x7FFFu + ((u >> 16) & 1u)) >> 16);  // RNE
}
// dtype-dispatched load/store: bf=1 -> bf16, bf=0 -> fp32
__device__ __forceinline__ float ldf(const void* p, long i, int bf) {
  return bf ? bf1(((const u16*)p)[i]) : ((const float*)p)[i];
}
__device__ __forceinline__ void stf(void* p, long i, int bf, float v) {
  if (bf) ((u16*)p)[i] = fbf(v); else ((float*)p)[i] = v;
}

// ---------- K0: dtype detect ----------
// If the buffer is fp32, decoding raw u16 halves as bf16 yields huge/NaN values
// (~12% of low halves). True bf16 N(0,1) data never exceeds ~5.
__global__ void k_detect(const void* __restrict__ probe, int* __restrict__ flag) {
  int th = threadIdx.x;  // 64
  int bad = 0;
  for (int i = th; i < 512; i += 64) {
    float v = bf1(((const u16*)probe)[i]);
    if (!(fabsf(v) < 1e10f)) bad = 1;  // catches inf/NaN too
  }
  int anybad = __any(bad);
  if (th == 0) flag[0] = anybad ? 0 : 1;
}

// ---------- K1: degrees (counts; clamp applied at use) ----------
__global__ __launch_bounds__(256) void k_deg(
    const int* __restrict__ pins_src, const int* __restrict__ pins_dst,
    const int* __restrict__ pinned_dst, const int* __restrict__ pf_dst,
    const int* __restrict__ connect_src, const int* __restrict__ connect_dst,
    const int* __restrict__ pt_src, const int* __restrict__ pt_dst,
    float* c_pins_src, float* c_pins_dst, float* c_pinned_dst, float* c_pf_dst,
    float* c_connect_src, float* c_connect_dst, float* c_pt_src, float* c_pt_dst) {
  int e = blockIdx.x * 256 + threadIdx.x;
  if (e >= NE) return;
  atomicAdd(&c_pins_src[pins_src[e]], 1.f);
  atomicAdd(&c_pins_dst[pins_dst[e]], 1.f);
  atomicAdd(&c_pinned_dst[pinned_dst[e]], 1.f);
  atomicAdd(&c_pf_dst[pf_dst[e]], 1.f);
  atomicAdd(&c_connect_src[connect_src[e]], 1.f);
  atomicAdd(&c_connect_dst[connect_dst[e]], 1.f);
  atomicAdd(&c_pt_src[pt_src[e]], 1.f);
  atomicAdd(&c_pt_dst[pt_dst[e]], 1.f);
}

// ---------- K2: graph-conv scatter: S[dst] += feat[src] * deg_src^-1/2 ----------
__global__ __launch_bounds__(256) void k_gc_scatter(
    const int* __restrict__ src, const int* __restrict__ dst,
    const void* __restrict__ feat, const float* __restrict__ cnt_src,
    float* __restrict__ S, const int* __restrict__ flag) {
  int t = blockIdx.x * 256 + threadIdx.x;
  int e = t >> 5, o = t & 31;
  if (e >= NE) return;
  int bf = flag[0];
  int s = src[e], d = dst[e];
  float w = rsqrtf(fmaxf(cnt_src[s], 1.f));
  float v = ldf(feat, (long)s * 32 + o, bf) * w;
  atomicAdd(&S[d * 32 + o], v);
}

// ---------- K3: per-source-node NNConv transform ----------
// T[s][o*16+p] = sum_i h[s,i] * W_topo[p, i*32+o]   (bf16 out, [s][o][p] layout)
__global__ __launch_bounds__(512) void k_transform(
    const void* __restrict__ feat, const void* __restrict__ W_topo,
    u16* __restrict__ T, int n, const int* __restrict__ flag) {
  int bf = flag[0];
  int j = threadIdx.x;  // 0..511
  int p = j & 15, o = j >> 4;
  float w[32];
#pragma unroll
  for (int i = 0; i < 32; i++) w[i] = ldf(W_topo, p * 1024 + i * 32 + o, bf);

  __shared__ float hs[4][32];
  int per = (n + gridDim.x - 1) / gridDim.x;
  int s0 = blockIdx.x * per;
  int s1 = min(s0 + per, n);
  for (int s = s0; s < s1; s += 4) {
    __syncthreads();
    if (threadIdx.x < 128) {
      int r = threadIdx.x >> 5, i = threadIdx.x & 31;
      int sn = s + r;
      hs[r][i] = (sn < s1) ? ldf(feat, (long)sn * 32 + i, bf) : 0.f;
    }
    __syncthreads();
#pragma unroll
    for (int r = 0; r < 4; r++) {
      int sn = s + r;
      if (sn >= s1) break;
      float acc = 0.f;
#pragma unroll
      for (int i = 0; i < 32; i++) acc += hs[r][i] * w[i];
      T[(size_t)sn * 512 + j] = fbf(acc);
    }
  }
}

// ---------- K3b: C[s,o] = sum_i h[s,i] * b_topo[i*32+o] ----------
__global__ __launch_bounds__(256) void k_C(
    const void* __restrict__ feat, const void* __restrict__ b_topo,
    float* __restrict__ C, int n, const int* __restrict__ flag) {
  int t = blockIdx.x * 256 + threadIdx.x;
  if (t >= n * 32) return;
  int bf = flag[0];
  int s = t >> 5, o = t & 31;
  float acc = 0.f;
#pragma unroll 8
  for (int i = 0; i < 32; i++)
    acc += ldf(feat, (long)s * 32 + i, bf) * ldf(b_topo, i * 32 + o, bf);
  C[t] = acc;
}

// ---------- K4: NNConv edge phase (FULL path, uses precomputed T) ----------
__global__ __launch_bounds__(256) void k_nnconv_edge(
    const int* __restrict__ src, const int* __restrict__ dst,
    const void* __restrict__ efeat, const u16* __restrict__ T,
    const float* __restrict__ C, const float* __restrict__ cnt_dst,
    float* __restrict__ ACC, const int* __restrict__ flag) {
  int t = blockIdx.x * 256 + threadIdx.x;
  int e = t >> 5, o = t & 31;
  if (e >= NE) return;
  int bf = flag[0];
  int s = src[e], d = dst[e];
  const u16* tp = T + (size_t)s * 512 + o * 16;
  float m = C[s * 32 + o];
#pragma unroll
  for (int p = 0; p < 16; p++)
    m += ldf(efeat, (long)e * 16 + p, bf) * bf1(tp[p]);
  m *= 1.0f / fmaxf(cnt_dst[d], 1.f);
  atomicAdd(&ACC[d * 32 + o], m);
}

// ---------- K4': NNConv edge phase (BASIC path, no T — small workspace) ----------
__global__ __launch_bounds__(256) void k_edge_direct(
    const int* __restrict__ src, const int* __restrict__ dst,
    const void* __restrict__ hfeat, const void* __restrict__ efeat,
    const void* __restrict__ W_topo, const void* __restrict__ b_topo,
    const float* __restrict__ cnt_dst, float* __restrict__ ACC,
    const int* __restrict__ flag) {
  int t = blockIdx.x * 256 + threadIdx.x;
  int e = t >> 5, o = t & 31;
  if (e >= NE) return;
  int bf = flag[0];
  int s = src[e], d = dst[e];
  float h[32];
#pragma unroll
  for (int i = 0; i < 32; i++) h[i] = ldf(hfeat, (long)s * 32 + i, bf);
  float acc = 0.f;
#pragma unroll 4
  for (int i = 0; i < 32; i++) acc += h[i] * ldf(b_topo, i * 32 + o, bf);
  for (int p = 0; p < 16; p++) {
    float dotv = 0.f;
#pragma unroll 8
    for (int i = 0; i < 32; i++) dotv += h[i] * ldf(W_topo, p * 1024 + i * 32 + o, bf);
    acc += ldf(efeat, (long)e * 16 + p, bf) * dotv;
  }
  acc *= 1.0f / fmaxf(cnt_dst[d], 1.f);
  atomicAdd(&ACC[d * 32 + o], acc);
}

// ---------- K5a: finalize net ----------
__global__ __launch_bounds__(256) void k_fin_net(
    const float* __restrict__ S, const void* __restrict__ net_feat,
    const void* __restrict__ W_pins, const void* __restrict__ b_pins,
    const void* __restrict__ W_net, const void* __restrict__ b_net,
    const float* __restrict__ cnt_dst, void* __restrict__ out,
    const int* __restrict__ flag) {
  int bf = flag[0];
  __shared__ float Wp[1024], Wn[1024];
  for (int k = threadIdx.x; k < 1024; k += 256) {
    Wp[k] = ldf(W_pins, k, bf);
    Wn[k] = ldf(W_net, k, bf);
  }
  __syncthreads();
  int t = blockIdx.x * 256 + threadIdx.x;
  int r = t >> 5, o = t & 31;
  if (r >= NN) return;
  float a1 = 0.f, a2 = 0.f;
#pragma unroll 8
  for (int i = 0; i < 32; i++) {
    a1 += S[r * 32 + i] * Wp[i * 32 + o];
    a2 += ldf(net_feat, (long)r * 32 + i, bf) * Wn[i * 32 + o];
  }
  float res = a1 * rsqrtf(fmaxf(cnt_dst[r], 1.f)) + ldf(b_pins, o, bf) +
              a2 + ldf(b_net, o, bf);
  stf(out, 1600000 + (long)r * 32 + o, bf, res);
}

// ---------- K5b: finalize gcell ----------
__global__ __launch_bounds__(256) void k_fin_gcell(
    const float* __restrict__ Sc, const float* __restrict__ Sp,
    const void* __restrict__ W_connect, const void* __restrict__ b_connect,
    const void* __restrict__ W_pt, const void* __restrict__ b_pt,
    const float* __restrict__ cnt_c, const float* __restrict__ cnt_p,
    void* __restrict__ out, const int* __restrict__ flag) {
  int bf = flag[0];
  __shared__ float Wc[1024], Wq[1024];
  for (int k = threadIdx.x; k < 1024; k += 256) {
    Wc[k] = ldf(W_connect, k, bf);
    Wq[k] = ldf(W_pt, k, bf);
  }
  __syncthreads();
  int t = blockIdx.x * 256 + threadIdx.x;
  int r = t >> 5, o = t & 31;
  if (r >= NG) return;
  float a1 = 0.f, a2 = 0.f;
#pragma unroll 8
  for (int i = 0; i < 32; i++) {
    a1 += Sc[r * 32 + i] * Wc[i * 32 + o];
    a2 += Sp[r * 32 + i] * Wq[i * 32 + o];
  }
  float res = a1 * rsqrtf(fmaxf(cnt_c[r], 1.f)) + ldf(b_connect, o, bf) +
              a2 * rsqrtf(fmaxf(cnt_p[r], 1.f)) + ldf(b_pt, o, bf);
  stf(out, 1920000 + (long)r * 32 + o, bf, res);
}

// ---------- K5c: finalize cell ----------
__global__ __launch_bounds__(256) void k_fin_cell(
    const float* __restrict__ ACC, const void* __restrict__ b_pinned,
    const void* __restrict__ b_pf, void* __restrict__ out,
    const int* __restrict__ flag) {
  int t = blockIdx.x * 256 + threadIdx.x;
  if (t >= NC * 32) return;
  int bf = flag[0];
  int o = t & 31;
  stf(out, t, bf, ACC[t] + ldf(b_pinned, o, bf) + ldf(b_pf, o, bf));
}

extern "C" void kernel_launch(void* const* d_in, const int* in_sizes, int n_in,
                              void* d_out, int out_size, void* d_ws, size_t ws_size,
                              hipStream_t stream) {
  const void* node_feat  = d_in[0];
  const void* net_feat   = d_in[1];
  const void* pin_feat   = d_in[2];
  const void* hanna_feat = d_in[3];
  const void* edge_feat  = d_in[4];
  const int* pins_src    = (const int*)d_in[5];
  const int* pins_dst    = (const int*)d_in[6];
  const int* pinned_src  = (const int*)d_in[7];
  const int* pinned_dst  = (const int*)d_in[8];
  const int* connect_src = (const int*)d_in[9];
  const int* connect_dst = (const int*)d_in[10];
  const int* pt_src      = (const int*)d_in[11];
  const int* pt_dst      = (const int*)d_in[12];
  const int* pf_src      = (const int*)d_in[13];
  const int* pf_dst      = (const int*)d_in[14];
  const void* W_net     = d_in[15];
  const void* b_net     = d_in[16];
  const void* W_topo    = d_in[17];
  const void* b_topo    = d_in[18];
  const void* W_pins    = d_in[19];
  const void* b_pins    = d_in[20];
  const void* W_connect = d_in[21];
  const void* b_connect = d_in[22];
  const void* W_pt      = d_in[23];
  const void* b_pt      = d_in[24];
  const void* b_pinned  = d_in[25];
  const void* b_pf      = d_in[26];

  // ---- workspace layout (float offsets; first 16 floats = flags) ----
  float* ws = (float*)d_ws;
  int*   flag          = (int*)d_ws;       // ws[0]
  float* c_pins_src    = ws + 16;          // NC
  float* c_pins_dst    = ws + 50016;       // NN
  float* c_pinned_dst  = ws + 60016;       // NC
  float* c_pf_dst      = ws + 110016;      // NC
  float* c_connect_src = ws + 160016;      // NG
  float* c_connect_dst = ws + 180016;      // NG
  float* c_pt_src      = ws + 200016;      // NC
  float* c_pt_dst      = ws + 250016;      // NG
  float* S_net    = ws + 270016;           // NN*32
  float* S_conn   = ws + 590016;           // NG*32
  float* S_pt     = ws + 1230016;          // NG*32
  float* ACC_cell = ws + 1870016;          // NC*32   -> zeroed region ends 3470016
  float* C_net    = ws + 3470016;          // NN*32 (fully written)
  float* C_hanna  = ws + 3790016;          // NG*32 (fully written)  end 4430016
  u16* T_net   = (u16*)((char*)d_ws + 17720064);              // NN*512 bf16
  u16* T_hanna = (u16*)((char*)d_ws + 17720064 + 10240000);   // NG*512 bf16
  const size_t FULL_NEED = 17720064 + 10240000 + 20480000;    // 48,440,064 B
  const bool full = (ws_size >= FULL_NEED);

  // zero flags + counts + S_* + ACC_cell
  hipMemsetAsync(d_ws, 0, 3470016 * sizeof(float), stream);

  k_detect<<<1, 64, 0, stream>>>(node_feat, flag);

  k_deg<<<(NE + 255) / 256, 256, 0, stream>>>(
      pins_src, pins_dst, pinned_dst, pf_dst, connect_src, connect_dst, pt_src, pt_dst,
      c_pins_src, c_pins_dst, c_pinned_dst, c_pf_dst,
      c_connect_src, c_connect_dst, c_pt_src, c_pt_dst);

  k_gc_scatter<<<(NE * 32 + 255) / 256, 256, 0, stream>>>(
      pins_src, pins_dst, node_feat, c_pins_src, S_net, flag);
  k_gc_scatter<<<(NE * 32 + 255) / 256, 256, 0, stream>>>(
      connect_src, connect_dst, hanna_feat, c_connect_src, S_conn, flag);
  k_gc_scatter<<<(NE * 32 + 255) / 256, 256, 0, stream>>>(
      pt_src, pt_dst, node_feat, c_pt_src, S_pt, flag);

  if (full) {
    k_transform<<<(NN + 31) / 32, 512, 0, stream>>>(net_feat, W_topo, T_net, NN, flag);
    k_transform<<<(NG + 31) / 32, 512, 0, stream>>>(hanna_feat, W_topo, T_hanna, NG, flag);
    k_C<<<(NN * 32 + 255) / 256, 256, 0, stream>>>(net_feat, b_topo, C_net, NN, flag);
    k_C<<<(NG * 32 + 255) / 256, 256, 0, stream>>>(hanna_feat, b_topo, C_hanna, NG, flag);
    k_nnconv_edge<<<(NE * 32 + 255) / 256, 256, 0, stream>>>(
        pinned_src, pinned_dst, pin_feat, T_net, C_net, c_pinned_dst, ACC_cell, flag);
    k_nnconv_edge<<<(NE * 32 + 255) / 256, 256, 0, stream>>>(
        pf_src, pf_dst, edge_feat, T_hanna, C_hanna, c_pf_dst, ACC_cell, flag);
  } else {
    k_edge_direct<<<(NE * 32 + 255) / 256, 256, 0, stream>>>(
        pinned_src, pinned_dst, net_feat, pin_feat, W_topo, b_topo,
        c_pinned_dst, ACC_cell, flag);
    k_edge_direct<<<(NE * 32 + 255) / 256, 256, 0, stream>>>(
        pf_src, pf_dst, hanna_feat, edge_feat, W_topo, b_topo,
        c_pf_dst, ACC_cell, flag);
  }

  k_fin_net<<<(NN * 32 + 255) / 256, 256, 0, stream>>>(
      S_net, net_feat, W_pins, b_pins, W_net, b_net, c_pins_dst, d_out, flag);
  k_fin_gcell<<<(NG * 32 + 255) / 256, 256, 0, stream>>>(
      S_conn, S_pt, W_connect, b_connect, W_pt, b_pt, c_connect_dst, c_pt_dst,
      d_out, flag);
  k_fin_cell<<<(NC * 32 + 255) / 256, 256, 0, stream>>>(
      ACC_cell, b_pinned, b_pf, d_out, flag);
}

// Round 5
// 389.431 us; speedup vs baseline: 1.2560x; 1.2560x over previous
//
#include <hip/hip_runtime.h>

typedef unsigned short u16;
typedef unsigned int u32;

#define NC 50000
#define NN 10000
#define NG 20000
#define NE 100000

// ---------- bf16 helpers: used ONLY for the workspace T tables ----------
__device__ __forceinline__ float bf1(u16 a) { return __uint_as_float(((u32)a) << 16); }
__device__ __forceinline__ float bflo(u32 a) { return __uint_as_float(a << 16); }
__device__ __forceinline__ float bfhi(u32 a) { return __uint_as_float(a & 0xFFFF0000u); }
__device__ __forceinline__ u16 fbf(float f) {
  u32 u = __float_as_uint(f);
  return (u16)((u + 0x7FFFu + ((u >> 16) & 1u)) >> 16);  // RNE
}

// ---------- K1: degrees (counts; clamp applied at use) ----------
__global__ __launch_bounds__(256) void k_deg(
    const int* __restrict__ pins_src, const int* __restrict__ pins_dst,
    const int* __restrict__ pinned_dst, const int* __restrict__ pf_dst,
    const int* __restrict__ connect_src, const int* __restrict__ connect_dst,
    const int* __restrict__ pt_src, const int* __restrict__ pt_dst,
    float* c_pins_src, float* c_pins_dst, float* c_pinned_dst, float* c_pf_dst,
    float* c_connect_src, float* c_connect_dst, float* c_pt_src, float* c_pt_dst) {
  int e = blockIdx.x * 256 + threadIdx.x;
  if (e >= NE) return;
  atomicAdd(&c_pins_src[pins_src[e]], 1.f);
  atomicAdd(&c_pins_dst[pins_dst[e]], 1.f);
  atomicAdd(&c_pinned_dst[pinned_dst[e]], 1.f);
  atomicAdd(&c_pf_dst[pf_dst[e]], 1.f);
  atomicAdd(&c_connect_src[connect_src[e]], 1.f);
  atomicAdd(&c_connect_dst[connect_dst[e]], 1.f);
  atomicAdd(&c_pt_src[pt_src[e]], 1.f);
  atomicAdd(&c_pt_dst[pt_dst[e]], 1.f);
}

// ---------- K2: fused graph-conv scatters (3 graphs, 8 threads/edge, float4) ----------
__global__ __launch_bounds__(256) void k_scatter(
    const int* __restrict__ pins_src, const int* __restrict__ pins_dst,
    const int* __restrict__ connect_src, const int* __restrict__ connect_dst,
    const int* __restrict__ pt_src, const int* __restrict__ pt_dst,
    const float* __restrict__ node_feat, const float* __restrict__ hanna_feat,
    const float* __restrict__ c_pins_src, const float* __restrict__ c_connect_src,
    const float* __restrict__ c_pt_src,
    float* __restrict__ S_net, float* __restrict__ S_conn, float* __restrict__ S_pt) {
  int t = blockIdx.x * 256 + threadIdx.x;  // < 2.4M
  if (t >= 3 * NE * 8) return;
  int e3 = t >> 3, q = t & 7;  // q: which float4 of the 32-float row
  int g = (e3 >= NE) + (e3 >= 2 * NE);  // 0=pins 1=connect 2=pt
  int e = e3 - g * NE;
  const int* src = g == 0 ? pins_src : (g == 1 ? connect_src : pt_src);
  const int* dst = g == 0 ? pins_dst : (g == 1 ? connect_dst : pt_dst);
  const float* feat = (g == 1) ? hanna_feat : node_feat;
  const float* cnt = g == 0 ? c_pins_src : (g == 1 ? c_connect_src : c_pt_src);
  float* S = g == 0 ? S_net : (g == 1 ? S_conn : S_pt);
  int s = src[e], d = dst[e];
  float w = rsqrtf(fmaxf(cnt[s], 1.f));
  float4 v = *reinterpret_cast<const float4*>(feat + (size_t)s * 32 + q * 4);
  float* Sd = S + (size_t)d * 32 + q * 4;
  atomicAdd(&Sd[0], v.x * w);
  atomicAdd(&Sd[1], v.y * w);
  atomicAdd(&Sd[2], v.z * w);
  atomicAdd(&Sd[3], v.w * w);
}

// ---------- K3: fused per-source-node NNConv transforms ----------
// T[s][o*16+p] = sum_i h[s,i] * W_topo[p, i*32+o]   (bf16 out, [s][o][p] layout)
// blocks 0..312 -> net (NN), 313..937 -> hanna (NG); 32 nodes/block
__global__ __launch_bounds__(512) void k_transform(
    const float* __restrict__ feat_net, const float* __restrict__ feat_han,
    const float* __restrict__ W_topo,
    u16* __restrict__ T_net, u16* __restrict__ T_han) {
  bool han = blockIdx.x >= 313;
  const float* feat = han ? feat_han : feat_net;
  u16* T = han ? T_han : T_net;
  int n = han ? NG : NN;
  int blk = han ? (blockIdx.x - 313) : blockIdx.x;
  int j = threadIdx.x;  // 0..511
  int p = j & 15, o = j >> 4;
  float w[32];
#pragma unroll
  for (int i = 0; i < 32; i++) w[i] = W_topo[p * 1024 + i * 32 + o];

  __shared__ float hs[4][32];
  int s0 = blk * 32;
  int s1 = min(s0 + 32, n);
  for (int s = s0; s < s1; s += 4) {
    __syncthreads();
    if (threadIdx.x < 128) {
      int r = threadIdx.x >> 5, i = threadIdx.x & 31;
      int sn = s + r;
      hs[r][i] = (sn < s1) ? feat[(size_t)sn * 32 + i] : 0.f;
    }
    __syncthreads();
#pragma unroll
    for (int r = 0; r < 4; r++) {
      int sn = s + r;
      if (sn >= s1) break;
      float acc = 0.f;
#pragma unroll
      for (int i = 0; i < 32; i++) acc += hs[r][i] * w[i];
      T[(size_t)sn * 512 + j] = fbf(acc);
    }
  }
}

// ---------- K3b: fused C[s,o] = sum_i h[s,i] * b_topo[i*32+o] ----------
__global__ __launch_bounds__(256) void k_C(
    const float* __restrict__ feat_net, const float* __restrict__ feat_han,
    const float* __restrict__ b_topo,
    float* __restrict__ C_net, float* __restrict__ C_han) {
  int t = blockIdx.x * 256 + threadIdx.x;
  if (t >= (NN + NG) * 32) return;
  int s2 = t >> 5, o = t & 31;
  bool han = s2 >= NN;
  const float* feat = han ? feat_han : feat_net;
  float* C = han ? C_han : C_net;
  int s = han ? s2 - NN : s2;
  float acc = 0.f;
#pragma unroll 8
  for (int i = 0; i < 32; i++)
    acc += feat[(size_t)s * 32 + i] * b_topo[i * 32 + o];
  C[(size_t)s * 32 + o] = acc;
}

// ---------- K4: fused NNConv edge phase (both convs) ----------
// m[e,o] = C[s,o] + sum_p ef[e,p] * T[s][o*16+p];  ACC[d,o] += m/deg
__global__ __launch_bounds__(256) void k_nnconv(
    const int* __restrict__ src0, const int* __restrict__ dst0,
    const float* __restrict__ ef0, const u16* __restrict__ T0,
    const float* __restrict__ C0, const float* __restrict__ cnt0,
    const int* __restrict__ src1, const int* __restrict__ dst1,
    const float* __restrict__ ef1, const u16* __restrict__ T1,
    const float* __restrict__ C1, const float* __restrict__ cnt1,
    float* __restrict__ ACC) {
  int t = blockIdx.x * 256 + threadIdx.x;
  int e2 = t >> 5, o = t & 31;
  if (e2 >= 2 * NE) return;
  bool sec = e2 >= NE;
  int e = sec ? e2 - NE : e2;
  const int* src = sec ? src1 : src0;
  const int* dst = sec ? dst1 : dst0;
  const float* ef = sec ? ef1 : ef0;
  const u16* T = sec ? T1 : T0;
  const float* C = sec ? C1 : C0;
  const float* cnt = sec ? cnt1 : cnt0;
  int s = src[e], d = dst[e];
  // ef row: 16 fp32, 64B-aligned (input base 256B-aligned)
  const float4* efp = reinterpret_cast<const float4*>(ef + (size_t)e * 16);
  float4 ea = efp[0], eb = efp[1], ec = efp[2], ed = efp[3];
  // T row slice: 16 bf16 = 32B, aligned (ws base 256B-aligned, offsets mult of 32B)
  const uint4* tp = reinterpret_cast<const uint4*>(T + (size_t)s * 512 + o * 16);
  uint4 ta = tp[0], tb = tp[1];
  float m = C[(size_t)s * 32 + o];
  m += ea.x * bflo(ta.x) + ea.y * bfhi(ta.x) + ea.z * bflo(ta.y) + ea.w * bfhi(ta.y);
  m += eb.x * bflo(ta.z) + eb.y * bfhi(ta.z) + eb.z * bflo(ta.w) + eb.w * bfhi(ta.w);
  m += ec.x * bflo(tb.x) + ec.y * bfhi(tb.x) + ec.z * bflo(tb.y) + ec.w * bfhi(tb.y);
  m += ed.x * bflo(tb.z) + ed.y * bfhi(tb.z) + ed.z * bflo(tb.w) + ed.w * bfhi(tb.w);
  m *= 1.0f / fmaxf(cnt[d], 1.f);
  atomicAdd(&ACC[(size_t)d * 32 + o], m);
}

// ---------- K5: fused finalize (cell | net | gcell by block range) ----------
__global__ __launch_bounds__(256) void k_fin(
    const float* __restrict__ ACC,
    const float* __restrict__ b_pinned, const float* __restrict__ b_pf,
    const float* __restrict__ S_net, const float* __restrict__ net_feat,
    const float* __restrict__ W_pins, const float* __restrict__ b_pins,
    const float* __restrict__ W_net, const float* __restrict__ b_net,
    const float* __restrict__ c_pins_dst,
    const float* __restrict__ S_conn, const float* __restrict__ S_pt,
    const float* __restrict__ W_connect, const float* __restrict__ b_connect,
    const float* __restrict__ W_pt, const float* __restrict__ b_pt,
    const float* __restrict__ c_connect_dst, const float* __restrict__ c_pt_dst,
    float* __restrict__ out) {
  __shared__ float Wa[1024], Wb[1024];
  int b = blockIdx.x;
  if (b < 6250) {  // cell: NC*32 = 1,600,000 elements
    int t = b * 256 + threadIdx.x;
    int o = t & 31;
    out[t] = ACC[t] + b_pinned[o] + b_pf[o];
    return;
  }
  if (b < 7500) {  // net: NN*32 = 320,000
    for (int k = threadIdx.x; k < 1024; k += 256) {
      Wa[k] = W_pins[k];
      Wb[k] = W_net[k];
    }
    __syncthreads();
    int t = (b - 6250) * 256 + threadIdx.x;
    int r = t >> 5, o = t & 31;
    float a1 = 0.f, a2 = 0.f;
#pragma unroll 8
    for (int i = 0; i < 32; i++) {
      a1 += S_net[(size_t)r * 32 + i] * Wa[i * 32 + o];
      a2 += net_feat[(size_t)r * 32 + i] * Wb[i * 32 + o];
    }
    out[1600000 + t] = a1 * rsqrtf(fmaxf(c_pins_dst[r], 1.f)) + b_pins[o] +
                       a2 + b_net[o];
    return;
  }
  // gcell: NG*32 = 640,000
  for (int k = threadIdx.x; k < 1024; k += 256) {
    Wa[k] = W_connect[k];
    Wb[k] = W_pt[k];
  }
  __syncthreads();
  int t = (b - 7500) * 256 + threadIdx.x;
  int r = t >> 5, o = t & 31;
  float a1 = 0.f, a2 = 0.f;
#pragma unroll 8
  for (int i = 0; i < 32; i++) {
    a1 += S_conn[(size_t)r * 32 + i] * Wa[i * 32 + o];
    a2 += S_pt[(size_t)r * 32 + i] * Wb[i * 32 + o];
  }
  out[1920000 + t] = a1 * rsqrtf(fmaxf(c_connect_dst[r], 1.f)) + b_connect[o] +
                     a2 * rsqrtf(fmaxf(c_pt_dst[r], 1.f)) + b_pt[o];
}

extern "C" void kernel_launch(void* const* d_in, const int* in_sizes, int n_in,
                              void* d_out, int out_size, void* d_ws, size_t ws_size,
                              hipStream_t stream) {
  const float* node_feat  = (const float*)d_in[0];
  const float* net_feat   = (const float*)d_in[1];
  const float* pin_feat   = (const float*)d_in[2];
  const float* hanna_feat = (const float*)d_in[3];
  const float* edge_feat  = (const float*)d_in[4];
  const int* pins_src    = (const int*)d_in[5];
  const int* pins_dst    = (const int*)d_in[6];
  const int* pinned_src  = (const int*)d_in[7];
  const int* pinned_dst  = (const int*)d_in[8];
  const int* connect_src = (const int*)d_in[9];
  const int* connect_dst = (const int*)d_in[10];
  const int* pt_src      = (const int*)d_in[11];
  const int* pt_dst      = (const int*)d_in[12];
  const int* pf_src      = (const int*)d_in[13];
  const int* pf_dst      = (const int*)d_in[14];
  const float* W_net     = (const float*)d_in[15];
  const float* b_net     = (const float*)d_in[16];
  const float* W_topo    = (const float*)d_in[17];
  const float* b_topo    = (const float*)d_in[18];
  const float* W_pins    = (const float*)d_in[19];
  const float* b_pins    = (const float*)d_in[20];
  const float* W_connect = (const float*)d_in[21];
  const float* b_connect = (const float*)d_in[22];
  const float* W_pt      = (const float*)d_in[23];
  const float* b_pt      = (const float*)d_in[24];
  const float* b_pinned  = (const float*)d_in[25];
  const float* b_pf      = (const float*)d_in[26];
  float* out = (float*)d_out;

  // ---- workspace layout (float offsets; same as round 2) ----
  float* ws = (float*)d_ws;
  float* c_pins_src    = ws + 16;          // NC
  float* c_pins_dst    = ws + 50016;       // NN
  float* c_pinned_dst  = ws + 60016;       // NC
  float* c_pf_dst      = ws + 110016;      // NC
  float* c_connect_src = ws + 160016;      // NG
  float* c_connect_dst = ws + 180016;      // NG
  float* c_pt_src      = ws + 200016;      // NC
  float* c_pt_dst      = ws + 250016;      // NG
  float* S_net    = ws + 270016;           // NN*32
  float* S_conn   = ws + 590016;           // NG*32
  float* S_pt     = ws + 1230016;          // NG*32
  float* ACC_cell = ws + 1870016;          // NC*32   -> zeroed region ends 3470016
  float* C_net    = ws + 3470016;          // NN*32 (fully written)
  float* C_hanna  = ws + 3790016;          // NG*32 (fully written)
  u16* T_net   = (u16*)((char*)d_ws + 17720064);              // NN*512 bf16
  u16* T_hanna = (u16*)((char*)d_ws + 17720064 + 10240000);   // NG*512 bf16

  // zero counts + S_* + ACC_cell
  hipMemsetAsync(d_ws, 0, 3470016 * sizeof(float), stream);

  k_deg<<<(NE + 255) / 256, 256, 0, stream>>>(
      pins_src, pins_dst, pinned_dst, pf_dst, connect_src, connect_dst, pt_src, pt_dst,
      c_pins_src, c_pins_dst, c_pinned_dst, c_pf_dst,
      c_connect_src, c_connect_dst, c_pt_src, c_pt_dst);

  k_transform<<<938, 512, 0, stream>>>(net_feat, hanna_feat, W_topo, T_net, T_hanna);

  k_C<<<((NN + NG) * 32 + 255) / 256, 256, 0, stream>>>(
      net_feat, hanna_feat, b_topo, C_net, C_hanna);

  k_scatter<<<(3 * NE * 8 + 255) / 256, 256, 0, stream>>>(
      pins_src, pins_dst, connect_src, connect_dst, pt_src, pt_dst,
      node_feat, hanna_feat, c_pins_src, c_connect_src, c_pt_src,
      S_net, S_conn, S_pt);

  k_nnconv<<<(2 * NE * 32) / 256, 256, 0, stream>>>(
      pinned_src, pinned_dst, pin_feat, T_net, C_net, c_pinned_dst,
      pf_src, pf_dst, edge_feat, T_hanna, C_hanna, c_pf_dst,
      ACC_cell);

  k_fin<<<10000, 256, 0, stream>>>(
      ACC_cell, b_pinned, b_pf,
      S_net, net_feat, W_pins, b_pins, W_net, b_net, c_pins_dst,
      S_conn, S_pt, W_connect, b_connect, W_pt, b_pt, c_connect_dst, c_pt_dst,
      out);
}

// Round 6
// 332.668 us; speedup vs baseline: 1.4703x; 1.1706x over previous
//
#include <hip/hip_runtime.h>

typedef unsigned short u16;
typedef unsigned int u32;

#define NC 50000
#define NN 10000
#define NG 20000
#define NE 100000
#define NSCAN 150016   // 5 dst-count regions (150,000) padded to 150,016
#define NBLK 74        // ceil(NSCAN / 2048)

// CSR dst regions inside hist/bases (element offsets):
// pins_dst    [0,      10000)   -> net rows
// connect_dst [10000,  30000)   -> gcell rows
// pt_dst      [30000,  50000)   -> gcell rows
// pinned_dst  [50000, 100000)   -> cell rows (conv0)
// pf_dst      [100000,150000)   -> cell rows (conv1)

// ---------- bf16 helpers (workspace T tables only) ----------
__device__ __forceinline__ float bflo(u32 a) { return __uint_as_float(a << 16); }
__device__ __forceinline__ float bfhi(u32 a) { return __uint_as_float(a & 0xFFFF0000u); }
__device__ __forceinline__ u16 fbf(float f) {
  u32 u = __float_as_uint(f);
  return (u16)((u + 0x7FFFu + ((u >> 16) & 1u)) >> 16);  // RNE
}

// ---------- K1: histograms (dst CSR counts + src degree counts), int ----------
__global__ __launch_bounds__(256) void k_hist(
    const int* __restrict__ pins_src, const int* __restrict__ pins_dst,
    const int* __restrict__ pinned_dst, const int* __restrict__ pf_dst,
    const int* __restrict__ connect_src, const int* __restrict__ connect_dst,
    const int* __restrict__ pt_src, const int* __restrict__ pt_dst,
    int* __restrict__ hist, int* __restrict__ srccnt) {
  int e = blockIdx.x * 256 + threadIdx.x;
  if (e >= NE) return;
  atomicAdd(&hist[pins_dst[e]], 1);
  atomicAdd(&hist[10000 + connect_dst[e]], 1);
  atomicAdd(&hist[30000 + pt_dst[e]], 1);
  atomicAdd(&hist[50000 + pinned_dst[e]], 1);
  atomicAdd(&hist[100000 + pf_dst[e]], 1);
  atomicAdd(&srccnt[pins_src[e]], 1);            // cell  [0,50000)
  atomicAdd(&srccnt[50000 + connect_src[e]], 1); // gcell [50000,70000)
  atomicAdd(&srccnt[70000 + pt_src[e]], 1);      // cell  [70000,120000)
}

// ---------- scan: 3-kernel exclusive prefix over hist (NSCAN) ----------
__global__ __launch_bounds__(256) void k_scan1(
    const int* __restrict__ cnt, int* __restrict__ bsum) {
  __shared__ int sm[256];
  int b = blockIdx.x, tid = threadIdx.x;
  int base = b * 2048 + tid * 8;
  int tot = 0;
#pragma unroll
  for (int j = 0; j < 8; j++) {
    int i = base + j;
    tot += (i < NSCAN) ? cnt[i] : 0;
  }
  sm[tid] = tot;
  __syncthreads();
  for (int off = 128; off > 0; off >>= 1) {
    if (tid < off) sm[tid] += sm[tid + off];
    __syncthreads();
  }
  if (tid == 0) bsum[b] = sm[0];
}

__global__ void k_scan2(int* __restrict__ bsum) {
  if (threadIdx.x == 0 && blockIdx.x == 0) {
    int run = 0;
    for (int b = 0; b < NBLK; b++) {
      int v = bsum[b];
      bsum[b] = run;
      run += v;
    }
  }
}

__global__ __launch_bounds__(256) void k_scan3(
    const int* __restrict__ cnt, const int* __restrict__ boff,
    int* __restrict__ bases) {
  __shared__ int sm[256];
  int b = blockIdx.x, tid = threadIdx.x;
  int base = b * 2048 + tid * 8;
  int v[8];
  int tot = 0;
#pragma unroll
  for (int j = 0; j < 8; j++) {
    int i = base + j;
    v[j] = (i < NSCAN) ? cnt[i] : 0;
    tot += v[j];
  }
  sm[tid] = tot;
  __syncthreads();
  for (int off = 1; off < 256; off <<= 1) {
    int add = (tid >= off) ? sm[tid - off] : 0;
    __syncthreads();
    sm[tid] += add;
    __syncthreads();
  }
  int excl = sm[tid] - tot + boff[b];
#pragma unroll
  for (int j = 0; j < 8; j++) {
    int i = base + j;
    if (i < NSCAN) bases[i] = excl;
    excl += v[j];
  }
}

// ---------- K2: fill CSR edge lists (int atomics on cursors) ----------
__global__ __launch_bounds__(256) void k_fill(
    const int* __restrict__ pins_dst, const int* __restrict__ connect_dst,
    const int* __restrict__ pt_dst, const int* __restrict__ pinned_dst,
    const int* __restrict__ pf_dst,
    const int* __restrict__ bases, int* __restrict__ cursor,
    int* __restrict__ idx_all) {
  int t = blockIdx.x * 256 + threadIdx.x;
  if (t >= 5 * NE) return;
  int r = t / NE, e = t - r * NE;
  const int* dsts = r == 0 ? pins_dst : r == 1 ? connect_dst
                   : r == 2 ? pt_dst : r == 3 ? pinned_dst : pf_dst;
  int off = r == 0 ? 0 : r == 1 ? 10000 : r == 2 ? 30000 : r == 3 ? 50000 : 100000;
  int g = off + dsts[e];
  int pos = atomicAdd(&cursor[g], 1);
  idx_all[bases[g] + pos] = e;
}

// ---------- K3: fused per-source-node NNConv transforms (proven in R5) ----------
// T[s][o*16+p] = sum_i h[s,i] * W_topo[p, i*32+o]   (bf16 out, [s][o][p] layout)
__global__ __launch_bounds__(512) void k_transform(
    const float* __restrict__ feat_net, const float* __restrict__ feat_han,
    const float* __restrict__ W_topo,
    u16* __restrict__ T_net, u16* __restrict__ T_han) {
  bool han = blockIdx.x >= 313;
  const float* feat = han ? feat_han : feat_net;
  u16* T = han ? T_han : T_net;
  int n = han ? NG : NN;
  int blk = han ? (blockIdx.x - 313) : blockIdx.x;
  int j = threadIdx.x;  // 0..511
  int p = j & 15, o = j >> 4;
  float w[32];
#pragma unroll
  for (int i = 0; i < 32; i++) w[i] = W_topo[p * 1024 + i * 32 + o];

  __shared__ float hs[4][32];
  int s0 = blk * 32;
  int s1 = min(s0 + 32, n);
  for (int s = s0; s < s1; s += 4) {
    __syncthreads();
    if (threadIdx.x < 128) {
      int r = threadIdx.x >> 5, i = threadIdx.x & 31;
      int sn = s + r;
      hs[r][i] = (sn < s1) ? feat[(size_t)sn * 32 + i] : 0.f;
    }
    __syncthreads();
#pragma unroll
    for (int r = 0; r < 4; r++) {
      int sn = s + r;
      if (sn >= s1) break;
      float acc = 0.f;
#pragma unroll
      for (int i = 0; i < 32; i++) acc += hs[r][i] * w[i];
      T[(size_t)sn * 512 + j] = fbf(acc);
    }
  }
}

// ---------- K3b: fused C[s,o] = sum_i h[s,i] * b_topo[i*32+o] (proven in R5) ----------
__global__ __launch_bounds__(256) void k_C(
    const float* __restrict__ feat_net, const float* __restrict__ feat_han,
    const float* __restrict__ b_topo,
    float* __restrict__ C_net, float* __restrict__ C_han) {
  int t = blockIdx.x * 256 + threadIdx.x;
  if (t >= (NN + NG) * 32) return;
  int s2 = t >> 5, o = t & 31;
  bool han = s2 >= NN;
  const float* feat = han ? feat_han : feat_net;
  float* C = han ? C_han : C_net;
  int s = han ? s2 - NN : s2;
  float acc = 0.f;
#pragma unroll 8
  for (int i = 0; i < 32; i++)
    acc += feat[(size_t)s * 32 + i] * b_topo[i * 32 + o];
  C[(size_t)s * 32 + o] = acc;
}

// ---------- K4: graph-conv GATHER (3 relations, 32 lanes/dst row, no atomics) ----------
__global__ __launch_bounds__(256) void k_gc_gather(
    const int* __restrict__ hist, const int* __restrict__ bases,
    const int* __restrict__ idx_all, const int* __restrict__ srccnt,
    const int* __restrict__ pins_src, const int* __restrict__ connect_src,
    const int* __restrict__ pt_src,
    const float* __restrict__ node_feat, const float* __restrict__ hanna_feat,
    float* __restrict__ S_net, float* __restrict__ S_conn, float* __restrict__ S_pt) {
  int t = blockIdx.x * 256 + threadIdx.x;
  int rr = t >> 5, o = t & 31;
  if (rr >= 50000) return;
  int rel = (rr >= 10000) + (rr >= 30000);
  const int* srcarr = rel == 0 ? pins_src : rel == 1 ? connect_src : pt_src;
  const float* feat = (rel == 1) ? hanna_feat : node_feat;
  const int* scnt = srccnt + (rel == 0 ? 0 : rel == 1 ? 50000 : 70000);
  float* S = rel == 0 ? S_net + (size_t)rr * 32
           : rel == 1 ? S_conn + (size_t)(rr - 10000) * 32
                      : S_pt + (size_t)(rr - 30000) * 32;
  int base = bases[rr], deg = hist[rr];
  float acc = 0.f;
  for (int k = 0; k < deg; k++) {
    int e = idx_all[base + k];
    int s = srcarr[e];
    float w = rsqrtf(fmaxf((float)scnt[s], 1.f));
    acc += feat[(size_t)s * 32 + o] * w;
  }
  S[o] = acc;
}

// ---------- K5: NNConv GATHER (both convs, 32 lanes/cell, writes d_out) ----------
__global__ __launch_bounds__(256) void k_nn_gather(
    const int* __restrict__ hist, const int* __restrict__ bases,
    const int* __restrict__ idx_all,
    const int* __restrict__ pinned_src, const int* __restrict__ pf_src,
    const float* __restrict__ pin_feat, const float* __restrict__ edge_feat,
    const u16* __restrict__ T_net, const u16* __restrict__ T_han,
    const float* __restrict__ C_net, const float* __restrict__ C_han,
    const float* __restrict__ b_pinned, const float* __restrict__ b_pf,
    float* __restrict__ out) {
  int t = blockIdx.x * 256 + threadIdx.x;
  int d = t >> 5, o = t & 31;
  if (d >= NC) return;
  float a0 = 0.f, a1 = 0.f;
  {  // conv0: 'pinned' net -> cell
    int g = 50000 + d;
    int base = bases[g], deg = hist[g];
    for (int k = 0; k < deg; k++) {
      int e = idx_all[base + k];
      int s = pinned_src[e];
      const float4* efp = reinterpret_cast<const float4*>(pin_feat + (size_t)e * 16);
      float4 ea = efp[0], eb = efp[1], ec = efp[2], ed = efp[3];
      const uint4* tp = reinterpret_cast<const uint4*>(T_net + (size_t)s * 512 + o * 16);
      uint4 ta = tp[0], tb = tp[1];
      float m = C_net[(size_t)s * 32 + o];
      m += ea.x * bflo(ta.x) + ea.y * bfhi(ta.x) + ea.z * bflo(ta.y) + ea.w * bfhi(ta.y);
      m += eb.x * bflo(ta.z) + eb.y * bfhi(ta.z) + eb.z * bflo(ta.w) + eb.w * bfhi(ta.w);
      m += ec.x * bflo(tb.x) + ec.y * bfhi(tb.x) + ec.z * bflo(tb.y) + ec.w * bfhi(tb.y);
      m += ed.x * bflo(tb.z) + ed.y * bfhi(tb.z) + ed.z * bflo(tb.w) + ed.w * bfhi(tb.w);
      a0 += m;
    }
    a0 /= fmaxf((float)deg, 1.f);
  }
  {  // conv1: 'point-from' gcell -> cell
    int g = 100000 + d;
    int base = bases[g], deg = hist[g];
    for (int k = 0; k < deg; k++) {
      int e = idx_all[base + k];
      int s = pf_src[e];
      const float4* efp = reinterpret_cast<const float4*>(edge_feat + (size_t)e * 16);
      float4 ea = efp[0], eb = efp[1], ec = efp[2], ed = efp[3];
      const uint4* tp = reinterpret_cast<const uint4*>(T_han + (size_t)s * 512 + o * 16);
      uint4 ta = tp[0], tb = tp[1];
      float m = C_han[(size_t)s * 32 + o];
      m += ea.x * bflo(ta.x) + ea.y * bfhi(ta.x) + ea.z * bflo(ta.y) + ea.w * bfhi(ta.y);
      m += eb.x * bflo(ta.z) + eb.y * bfhi(ta.z) + eb.z * bflo(ta.w) + eb.w * bfhi(ta.w);
      m += ec.x * bflo(tb.x) + ec.y * bfhi(tb.x) + ec.z * bflo(tb.y) + ec.w * bfhi(tb.y);
      m += ed.x * bflo(tb.z) + ed.y * bfhi(tb.z) + ed.z * bflo(tb.w) + ed.w * bfhi(tb.w);
      a1 += m;
    }
    a1 /= fmaxf((float)deg, 1.f);
  }
  out[(size_t)d * 32 + o] = a0 + a1 + b_pinned[o] + b_pf[o];
}

// ---------- K6: finalize net + gcell (cell handled by k_nn_gather) ----------
__global__ __launch_bounds__(256) void k_fin(
    const int* __restrict__ hist,
    const float* __restrict__ S_net, const float* __restrict__ net_feat,
    const float* __restrict__ W_pins, const float* __restrict__ b_pins,
    const float* __restrict__ W_net, const float* __restrict__ b_net,
    const float* __restrict__ S_conn, const float* __restrict__ S_pt,
    const float* __restrict__ W_connect, const float* __restrict__ b_connect,
    const float* __restrict__ W_pt, const float* __restrict__ b_pt,
    float* __restrict__ out) {
  __shared__ float Wa[1024], Wb[1024];
  int b = blockIdx.x;
  if (b < 1250) {  // net: NN*32 = 320,000
    for (int k = threadIdx.x; k < 1024; k += 256) {
      Wa[k] = W_pins[k];
      Wb[k] = W_net[k];
    }
    __syncthreads();
    int t = b * 256 + threadIdx.x;
    int r = t >> 5, o = t & 31;
    float a1 = 0.f, a2 = 0.f;
#pragma unroll 8
    for (int i = 0; i < 32; i++) {
      a1 += S_net[(size_t)r * 32 + i] * Wa[i * 32 + o];
      a2 += net_feat[(size_t)r * 32 + i] * Wb[i * 32 + o];
    }
    out[1600000 + t] = a1 * rsqrtf(fmaxf((float)hist[r], 1.f)) + b_pins[o] +
                       a2 + b_net[o];
    return;
  }
  // gcell: NG*32 = 640,000
  for (int k = threadIdx.x; k < 1024; k += 256) {
    Wa[k] = W_connect[k];
    Wb[k] = W_pt[k];
  }
  __syncthreads();
  int t = (b - 1250) * 256 + threadIdx.x;
  int r = t >> 5, o = t & 31;
  float a1 = 0.f, a2 = 0.f;
#pragma unroll 8
  for (int i = 0; i < 32; i++) {
    a1 += S_conn[(size_t)r * 32 + i] * Wa[i * 32 + o];
    a2 += S_pt[(size_t)r * 32 + i] * Wb[i * 32 + o];
  }
  out[1920000 + t] = a1 * rsqrtf(fmaxf((float)hist[10000 + r], 1.f)) + b_connect[o] +
                     a2 * rsqrtf(fmaxf((float)hist[30000 + r], 1.f)) + b_pt[o];
}

extern "C" void kernel_launch(void* const* d_in, const int* in_sizes, int n_in,
                              void* d_out, int out_size, void* d_ws, size_t ws_size,
                              hipStream_t stream) {
  const float* node_feat  = (const float*)d_in[0];
  const float* net_feat   = (const float*)d_in[1];
  const float* pin_feat   = (const float*)d_in[2];
  const float* hanna_feat = (const float*)d_in[3];
  const float* edge_feat  = (const float*)d_in[4];
  const int* pins_src    = (const int*)d_in[5];
  const int* pins_dst    = (const int*)d_in[6];
  const int* pinned_src  = (const int*)d_in[7];
  const int* pinned_dst  = (const int*)d_in[8];
  const int* connect_src = (const int*)d_in[9];
  const int* connect_dst = (const int*)d_in[10];
  const int* pt_src      = (const int*)d_in[11];
  const int* pt_dst      = (const int*)d_in[12];
  const int* pf_src      = (const int*)d_in[13];
  const int* pf_dst      = (const int*)d_in[14];
  const float* W_net     = (const float*)d_in[15];
  const float* b_net     = (const float*)d_in[16];
  const float* W_topo    = (const float*)d_in[17];
  const float* b_topo    = (const float*)d_in[18];
  const float* W_pins    = (const float*)d_in[19];
  const float* b_pins    = (const float*)d_in[20];
  const float* W_connect = (const float*)d_in[21];
  const float* b_connect = (const float*)d_in[22];
  const float* W_pt      = (const float*)d_in[23];
  const float* b_pt      = (const float*)d_in[24];
  const float* b_pinned  = (const float*)d_in[25];
  const float* b_pf      = (const float*)d_in[26];
  float* out = (float*)d_out;

  // ---- workspace layout ----
  // ints (element offsets from base):
  int* wi = (int*)d_ws;
  int* hist    = wi + 0;         // [0, 150016)        dst CSR counts (5 regions)
  int* cursor  = wi + 150016;    // [150016, 300032)   fill cursors
  int* srccnt  = wi + 300032;    // [300032, 420032)   src degree counts (3 regions)
  int* bases   = wi + 420032;    // [420032, 570064)   exclusive scan of hist
  int* bsum    = wi + 570064;    // [570064, 570192)   block sums (74 used)
  int* idx_all = wi + 570192;    // [570192, 1070192)  CSR edge ids (500,000)
  // floats:
  float* wf = (float*)d_ws;
  float* S_net  = wf + 1070192;  // NN*32 = 320,000
  float* S_conn = wf + 1390192;  // NG*32 = 640,000
  float* S_pt   = wf + 2030192;  // NG*32 = 640,000
  float* C_net  = wf + 2670192;  // NN*32 = 320,000
  float* C_han  = wf + 2990192;  // NG*32 = 640,000 -> float end 3,630,192 (byte 14,520,768)
  u16* T_net = (u16*)((char*)d_ws + 14520832);             // NN*512 bf16 (10,240,000 B)
  u16* T_han = (u16*)((char*)d_ws + 14520832 + 10240000);  // NG*512 bf16 (20,480,000 B)
  // total: 45,240,832 B  (< known-available 48,440,064 B)

  // zero hist + cursor + srccnt (first 420,032 ints)
  hipMemsetAsync(d_ws, 0, 420032 * sizeof(int), stream);

  k_hist<<<(NE + 255) / 256, 256, 0, stream>>>(
      pins_src, pins_dst, pinned_dst, pf_dst, connect_src, connect_dst,
      pt_src, pt_dst, hist, srccnt);

  k_scan1<<<NBLK, 256, 0, stream>>>(hist, bsum);
  k_scan2<<<1, 64, 0, stream>>>(bsum);
  k_scan3<<<NBLK, 256, 0, stream>>>(hist, bsum, bases);

  k_fill<<<(5 * NE + 255) / 256, 256, 0, stream>>>(
      pins_dst, connect_dst, pt_dst, pinned_dst, pf_dst, bases, cursor, idx_all);

  k_transform<<<938, 512, 0, stream>>>(net_feat, hanna_feat, W_topo, T_net, T_han);

  k_C<<<((NN + NG) * 32 + 255) / 256, 256, 0, stream>>>(
      net_feat, hanna_feat, b_topo, C_net, C_han);

  k_gc_gather<<<(50000 * 32) / 256, 256, 0, stream>>>(
      hist, bases, idx_all, srccnt, pins_src, connect_src, pt_src,
      node_feat, hanna_feat, S_net, S_conn, S_pt);

  k_nn_gather<<<(NC * 32) / 256, 256, 0, stream>>>(
      hist, bases, idx_all, pinned_src, pf_src, pin_feat, edge_feat,
      T_net, T_han, C_net, C_han, b_pinned, b_pf, out);

  k_fin<<<3750, 256, 0, stream>>>(
      hist, S_net, net_feat, W_pins, b_pins, W_net, b_net,
      S_conn, S_pt, W_connect, b_connect, W_pt, b_pt, out);
}

// Round 7
// 303.935 us; speedup vs baseline: 1.6093x; 1.0945x over previous
//
#include <hip/hip_runtime.h>

typedef unsigned short u16;
typedef unsigned int u32;

#define NC 50000
#define NN 10000
#define NG 20000
#define NE 100000
#define NSCAN 150016   // 5 dst-count regions (150,000) padded
#define NBLK 74        // ceil(NSCAN / 2048)

// CSR dst regions inside hist/bases (element offsets):
// pins_dst    [0,      10000)   -> net rows
// connect_dst [10000,  30000)   -> gcell rows
// pt_dst      [30000,  50000)   -> gcell rows
// pinned_dst  [50000, 100000)   -> cell rows (conv0)
// pf_dst      [100000,150000)   -> cell rows (conv1)

// ---------- bf16 helpers (workspace T tables only) ----------
__device__ __forceinline__ float bflo(u32 a) { return __uint_as_float(a << 16); }
__device__ __forceinline__ float bfhi(u32 a) { return __uint_as_float(a & 0xFFFF0000u); }
__device__ __forceinline__ u16 fbf(float f) {
  u32 u = __float_as_uint(f);
  return (u16)((u + 0x7FFFu + ((u >> 16) & 1u)) >> 16);  // RNE
}

// one NNConv edge message for lane-output o
__device__ __forceinline__ float nn_msg(int e, int s, const float* __restrict__ ef,
                                        const u16* __restrict__ T,
                                        const float* __restrict__ C, int o) {
  const float4* efp = reinterpret_cast<const float4*>(ef + (size_t)e * 16);
  float4 ea = efp[0], eb = efp[1], ec = efp[2], ed = efp[3];
  const uint4* tp = reinterpret_cast<const uint4*>(T + (size_t)s * 512 + o * 16);
  uint4 ta = tp[0], tb = tp[1];
  float m = C[(size_t)s * 32 + o];
  m += ea.x * bflo(ta.x) + ea.y * bfhi(ta.x) + ea.z * bflo(ta.y) + ea.w * bfhi(ta.y);
  m += eb.x * bflo(ta.z) + eb.y * bfhi(ta.z) + eb.z * bflo(ta.w) + eb.w * bfhi(ta.w);
  m += ec.x * bflo(tb.x) + ec.y * bfhi(tb.x) + ec.z * bflo(tb.y) + ec.w * bfhi(tb.y);
  m += ed.x * bflo(tb.z) + ed.y * bfhi(tb.z) + ed.z * bflo(tb.w) + ed.w * bfhi(tb.w);
  return m;
}

// ---------- K_FRONT: fused transform (938) | C (1875) | hist (196), 512 thr ----------
// transform: T[s][o*16+p] = sum_i h[s,i] * W_topo[p, i*32+o]  (bf16, [s][o][p])
//   h-row loads are wave-uniform -> scalar (SMEM) broadcast, no LDS, no syncs.
__global__ __launch_bounds__(512) void k_front(
    const float* __restrict__ feat_net, const float* __restrict__ feat_han,
    const float* __restrict__ W_topo, const float* __restrict__ b_topo,
    u16* __restrict__ T_net, u16* __restrict__ T_han,
    float* __restrict__ C_net, float* __restrict__ C_han,
    const int* __restrict__ pins_src, const int* __restrict__ pins_dst,
    const int* __restrict__ pinned_dst, const int* __restrict__ pf_dst,
    const int* __restrict__ connect_src, const int* __restrict__ connect_dst,
    const int* __restrict__ pt_src, const int* __restrict__ pt_dst,
    int* __restrict__ hist, int* __restrict__ srccnt) {
  int b = blockIdx.x;
  if (b < 938) {  // ---- transform ----
    bool han = b >= 313;
    const float* feat = han ? feat_han : feat_net;
    u16* T = han ? T_han : T_net;
    int n = han ? NG : NN;
    int blk = han ? b - 313 : b;
    int j = threadIdx.x;  // 0..511
    int p = j & 15, o = j >> 4;
    float w[32];
#pragma unroll
    for (int i = 0; i < 32; i++) w[i] = W_topo[p * 1024 + i * 32 + o];
    int s0 = blk * 32;
    int s1 = min(s0 + 32, n);
    int sn = s0;
    for (; sn + 1 < s1; sn += 2) {
      const float* h0 = feat + (size_t)sn * 32;  // wave-uniform rows
      const float* h1 = h0 + 32;
      float a0 = 0.f, a1 = 0.f;
#pragma unroll
      for (int i = 0; i < 32; i++) {
        a0 += h0[i] * w[i];
        a1 += h1[i] * w[i];
      }
      T[(size_t)sn * 512 + j] = fbf(a0);
      T[(size_t)(sn + 1) * 512 + j] = fbf(a1);
    }
    if (sn < s1) {
      const float* h0 = feat + (size_t)sn * 32;
      float a0 = 0.f;
#pragma unroll
      for (int i = 0; i < 32; i++) a0 += h0[i] * w[i];
      T[(size_t)sn * 512 + j] = fbf(a0);
    }
    return;
  }
  if (b < 2813) {  // ---- C: (NN+NG)*32 = 960,000 = 1875*512 exact ----
    int t = (b - 938) * 512 + threadIdx.x;
    int s2 = t >> 5, o = t & 31;
    bool han = s2 >= NN;
    const float* feat = han ? feat_han : feat_net;
    float* C = han ? C_han : C_net;
    int s = han ? s2 - NN : s2;
    float acc = 0.f;
#pragma unroll 8
    for (int i = 0; i < 32; i++)
      acc += feat[(size_t)s * 32 + i] * b_topo[i * 32 + o];
    C[(size_t)s * 32 + o] = acc;
    return;
  }
  // ---- hist ----
  int e = (b - 2813) * 512 + threadIdx.x;
  if (e >= NE) return;
  atomicAdd(&hist[pins_dst[e]], 1);
  atomicAdd(&hist[10000 + connect_dst[e]], 1);
  atomicAdd(&hist[30000 + pt_dst[e]], 1);
  atomicAdd(&hist[50000 + pinned_dst[e]], 1);
  atomicAdd(&hist[100000 + pf_dst[e]], 1);
  atomicAdd(&srccnt[pins_src[e]], 1);            // cell  [0,50000)
  atomicAdd(&srccnt[50000 + connect_src[e]], 1); // gcell [50000,70000)
  atomicAdd(&srccnt[70000 + pt_src[e]], 1);      // cell  [70000,120000)
}

// ---------- scan: 2 kernels (block sums; then per-block serial carry + local scan) ----------
__global__ __launch_bounds__(256) void k_scan1(
    const int* __restrict__ cnt, int* __restrict__ bsum) {
  __shared__ int sm[256];
  int b = blockIdx.x, tid = threadIdx.x;
  int base = b * 2048 + tid * 8;
  int tot = 0;
#pragma unroll
  for (int j = 0; j < 8; j++) {
    int i = base + j;
    tot += (i < NSCAN) ? cnt[i] : 0;
  }
  sm[tid] = tot;
  __syncthreads();
  for (int off = 128; off > 0; off >>= 1) {
    if (tid < off) sm[tid] += sm[tid + off];
    __syncthreads();
  }
  if (tid == 0) bsum[b] = sm[0];
}

__global__ __launch_bounds__(256) void k_scan3(
    const int* __restrict__ cnt, const int* __restrict__ bsum,
    int* __restrict__ bases) {
  __shared__ int sm[256];
  __shared__ int carry;
  int b = blockIdx.x, tid = threadIdx.x;
  if (tid == 0) {  // exclusive prefix of block sums up to b (74 adds, trivial)
    int run = 0;
    for (int i = 0; i < NBLK; i++) {
      if (i == b) break;
      run += bsum[i];
    }
    carry = run;
  }
  int base = b * 2048 + tid * 8;
  int v[8];
  int tot = 0;
#pragma unroll
  for (int j = 0; j < 8; j++) {
    int i = base + j;
    v[j] = (i < NSCAN) ? cnt[i] : 0;
    tot += v[j];
  }
  sm[tid] = tot;
  __syncthreads();
  for (int off = 1; off < 256; off <<= 1) {
    int add = (tid >= off) ? sm[tid - off] : 0;
    __syncthreads();
    sm[tid] += add;
    __syncthreads();
  }
  int excl = sm[tid] - tot + carry;
#pragma unroll
  for (int j = 0; j < 8; j++) {
    int i = base + j;
    if (i < NSCAN) bases[i] = excl;
    excl += v[j];
  }
}

// ---------- K_FILL: CSR edge lists (int atomics on cursors) ----------
__global__ __launch_bounds__(512) void k_fill(
    const int* __restrict__ pins_dst, const int* __restrict__ connect_dst,
    const int* __restrict__ pt_dst, const int* __restrict__ pinned_dst,
    const int* __restrict__ pf_dst,
    const int* __restrict__ bases, int* __restrict__ cursor,
    int* __restrict__ idx_all) {
  int t = blockIdx.x * 512 + threadIdx.x;
  if (t >= 5 * NE) return;
  int r = t / NE, e = t - r * NE;
  const int* dsts = r == 0 ? pins_dst : r == 1 ? connect_dst
                   : r == 2 ? pt_dst : r == 3 ? pinned_dst : pf_dst;
  int off = r == 0 ? 0 : r == 1 ? 10000 : r == 2 ? 30000 : r == 3 ? 50000 : 100000;
  int g = off + dsts[e];
  int pos = atomicAdd(&cursor[g], 1);
  idx_all[bases[g] + pos] = e;
}

// ---------- K_GC: graph-conv gather (3 relations, 32 lanes/dst row) ----------
__global__ __launch_bounds__(512) void k_gc_gather(
    const int* __restrict__ hist, const int* __restrict__ bases,
    const int* __restrict__ idx_all, const int* __restrict__ srccnt,
    const int* __restrict__ pins_src, const int* __restrict__ connect_src,
    const int* __restrict__ pt_src,
    const float* __restrict__ node_feat, const float* __restrict__ hanna_feat,
    float* __restrict__ S_net, float* __restrict__ S_conn, float* __restrict__ S_pt) {
  int t = blockIdx.x * 512 + threadIdx.x;  // 3125*512 = 1.6M exact
  int rr = t >> 5, o = t & 31;
  int rel = (rr >= 10000) + (rr >= 30000);
  const int* srcarr = rel == 0 ? pins_src : rel == 1 ? connect_src : pt_src;
  const float* feat = (rel == 1) ? hanna_feat : node_feat;
  const int* scnt = srccnt + (rel == 0 ? 0 : rel == 1 ? 50000 : 70000);
  float* S = rel == 0 ? S_net + (size_t)rr * 32
           : rel == 1 ? S_conn + (size_t)(rr - 10000) * 32
                      : S_pt + (size_t)(rr - 30000) * 32;
  int base = bases[rr], deg = hist[rr];
  float acc = 0.f;
  int k = 0;
  for (; k + 1 < deg; k += 2) {  // unroll-2: two independent load chains
    int ea = idx_all[base + k], eb = idx_all[base + k + 1];
    int sa = srcarr[ea], sb = srcarr[eb];
    float wa = rsqrtf(fmaxf((float)scnt[sa], 1.f));
    float wb = rsqrtf(fmaxf((float)scnt[sb], 1.f));
    acc += feat[(size_t)sa * 32 + o] * wa + feat[(size_t)sb * 32 + o] * wb;
  }
  if (k < deg) {
    int e = idx_all[base + k];
    int s = srcarr[e];
    acc += feat[(size_t)s * 32 + o] * rsqrtf(fmaxf((float)scnt[s], 1.f));
  }
  S[o] = acc;
}

// ---------- K_TAIL: nn_gather cells (3125) | net fin (625) | gcell fin (1250) ----------
__global__ __launch_bounds__(512) void k_tail(
    const int* __restrict__ hist, const int* __restrict__ bases,
    const int* __restrict__ idx_all,
    const int* __restrict__ pinned_src, const int* __restrict__ pf_src,
    const float* __restrict__ pin_feat, const float* __restrict__ edge_feat,
    const u16* __restrict__ T_net, const u16* __restrict__ T_han,
    const float* __restrict__ C_net, const float* __restrict__ C_han,
    const float* __restrict__ b_pinned, const float* __restrict__ b_pf,
    const float* __restrict__ S_net, const float* __restrict__ net_feat,
    const float* __restrict__ W_pins, const float* __restrict__ b_pins,
    const float* __restrict__ W_net, const float* __restrict__ b_net,
    const float* __restrict__ S_conn, const float* __restrict__ S_pt,
    const float* __restrict__ W_connect, const float* __restrict__ b_connect,
    const float* __restrict__ W_pt, const float* __restrict__ b_pt,
    float* __restrict__ out) {
  __shared__ float Wa[1024], Wb[1024];
  int b = blockIdx.x;
  if (b < 3125) {  // ---- NNConv gather: NC*32 = 1.6M = 3125*512 exact ----
    int t = b * 512 + threadIdx.x;
    int d = t >> 5, o = t & 31;
    float a0 = 0.f, a1 = 0.f;
    {  // conv0: 'pinned' net -> cell
      int g = 50000 + d;
      int base = bases[g], deg = hist[g];
      int k = 0;
      for (; k + 1 < deg; k += 2) {
        int ea = idx_all[base + k], eb = idx_all[base + k + 1];
        int sa = pinned_src[ea], sb = pinned_src[eb];
        a0 += nn_msg(ea, sa, pin_feat, T_net, C_net, o) +
              nn_msg(eb, sb, pin_feat, T_net, C_net, o);
      }
      if (k < deg) {
        int e = idx_all[base + k];
        a0 += nn_msg(e, pinned_src[e], pin_feat, T_net, C_net, o);
      }
      a0 /= fmaxf((float)deg, 1.f);
    }
    {  // conv1: 'point-from' gcell -> cell
      int g = 100000 + d;
      int base = bases[g], deg = hist[g];
      int k = 0;
      for (; k + 1 < deg; k += 2) {
        int ea = idx_all[base + k], eb = idx_all[base + k + 1];
        int sa = pf_src[ea], sb = pf_src[eb];
        a1 += nn_msg(ea, sa, edge_feat, T_han, C_han, o) +
              nn_msg(eb, sb, edge_feat, T_han, C_han, o);
      }
      if (k < deg) {
        int e = idx_all[base + k];
        a1 += nn_msg(e, pf_src[e], edge_feat, T_han, C_han, o);
      }
      a1 /= fmaxf((float)deg, 1.f);
    }
    out[(size_t)d * 32 + o] = a0 + a1 + b_pinned[o] + b_pf[o];
    return;
  }
  if (b < 3750) {  // ---- net fin: NN*32 = 320,000 = 625*512 exact ----
    for (int k = threadIdx.x; k < 1024; k += 512) {
      Wa[k] = W_pins[k];
      Wb[k] = W_net[k];
    }
    __syncthreads();
    int t = (b - 3125) * 512 + threadIdx.x;
    int r = t >> 5, o = t & 31;
    float a1 = 0.f, a2 = 0.f;
#pragma unroll 8
    for (int i = 0; i < 32; i++) {
      a1 += S_net[(size_t)r * 32 + i] * Wa[i * 32 + o];
      a2 += net_feat[(size_t)r * 32 + i] * Wb[i * 32 + o];
    }
    out[1600000 + t] = a1 * rsqrtf(fmaxf((float)hist[r], 1.f)) + b_pins[o] +
                       a2 + b_net[o];
    return;
  }
  // ---- gcell fin: NG*32 = 640,000 = 1250*512 exact ----
  for (int k = threadIdx.x; k < 1024; k += 512) {
    Wa[k] = W_connect[k];
    Wb[k] = W_pt[k];
  }
  __syncthreads();
  int t = (b - 3750) * 512 + threadIdx.x;
  int r = t >> 5, o = t & 31;
  float a1 = 0.f, a2 = 0.f;
#pragma unroll 8
  for (int i = 0; i < 32; i++) {
    a1 += S_conn[(size_t)r * 32 + i] * Wa[i * 32 + o];
    a2 += S_pt[(size_t)r * 32 + i] * Wb[i * 32 + o];
  }
  out[1920000 + t] = a1 * rsqrtf(fmaxf((float)hist[10000 + r], 1.f)) + b_connect[o] +
                     a2 * rsqrtf(fmaxf((float)hist[30000 + r], 1.f)) + b_pt[o];
}

extern "C" void kernel_launch(void* const* d_in, const int* in_sizes, int n_in,
                              void* d_out, int out_size, void* d_ws, size_t ws_size,
                              hipStream_t stream) {
  const float* node_feat  = (const float*)d_in[0];
  const float* net_feat   = (const float*)d_in[1];
  const float* pin_feat   = (const float*)d_in[2];
  const float* hanna_feat = (const float*)d_in[3];
  const float* edge_feat  = (const float*)d_in[4];
  const int* pins_src    = (const int*)d_in[5];
  const int* pins_dst    = (const int*)d_in[6];
  const int* pinned_src  = (const int*)d_in[7];
  const int* pinned_dst  = (const int*)d_in[8];
  const int* connect_src = (const int*)d_in[9];
  const int* connect_dst = (const int*)d_in[10];
  const int* pt_src      = (const int*)d_in[11];
  const int* pt_dst      = (const int*)d_in[12];
  const int* pf_src      = (const int*)d_in[13];
  const int* pf_dst      = (const int*)d_in[14];
  const float* W_net     = (const float*)d_in[15];
  const float* b_net     = (const float*)d_in[16];
  const float* W_topo    = (const float*)d_in[17];
  const float* b_topo    = (const float*)d_in[18];
  const float* W_pins    = (const float*)d_in[19];
  const float* b_pins    = (const float*)d_in[20];
  const float* W_connect = (const float*)d_in[21];
  const float* b_connect = (const float*)d_in[22];
  const float* W_pt      = (const float*)d_in[23];
  const float* b_pt      = (const float*)d_in[24];
  const float* b_pinned  = (const float*)d_in[25];
  const float* b_pf      = (const float*)d_in[26];
  float* out = (float*)d_out;

  // ---- workspace layout (identical to round 6; 45.24 MB total) ----
  int* wi = (int*)d_ws;
  int* hist    = wi + 0;         // [0, 150016)
  int* cursor  = wi + 150016;    // [150016, 300032)
  int* srccnt  = wi + 300032;    // [300032, 420032)
  int* bases   = wi + 420032;    // [420032, 570064)
  int* bsum    = wi + 570064;    // [570064, 570192)
  int* idx_all = wi + 570192;    // [570192, 1070192)
  float* wf = (float*)d_ws;
  float* S_net  = wf + 1070192;  // NN*32
  float* S_conn = wf + 1390192;  // NG*32
  float* S_pt   = wf + 2030192;  // NG*32
  float* C_net  = wf + 2670192;  // NN*32
  float* C_han  = wf + 2990192;  // NG*32 -> float end 3,630,192
  u16* T_net = (u16*)((char*)d_ws + 14520832);             // NN*512 bf16
  u16* T_han = (u16*)((char*)d_ws + 14520832 + 10240000);  // NG*512 bf16

  hipMemsetAsync(d_ws, 0, 420032 * sizeof(int), stream);  // hist+cursor+srccnt

  k_front<<<3009, 512, 0, stream>>>(
      net_feat, hanna_feat, W_topo, b_topo, T_net, T_han, C_net, C_han,
      pins_src, pins_dst, pinned_dst, pf_dst, connect_src, connect_dst,
      pt_src, pt_dst, hist, srccnt);

  k_scan1<<<NBLK, 256, 0, stream>>>(hist, bsum);
  k_scan3<<<NBLK, 256, 0, stream>>>(hist, bsum, bases);

  k_fill<<<(5 * NE + 511) / 512, 512, 0, stream>>>(
      pins_dst, connect_dst, pt_dst, pinned_dst, pf_dst, bases, cursor, idx_all);

  k_gc_gather<<<3125, 512, 0, stream>>>(
      hist, bases, idx_all, srccnt, pins_src, connect_src, pt_src,
      node_feat, hanna_feat, S_net, S_conn, S_pt);

  k_tail<<<5000, 512, 0, stream>>>(
      hist, bases, idx_all, pinned_src, pf_src, pin_feat, edge_feat,
      T_net, T_han, C_net, C_han, b_pinned, b_pf,
      S_net, net_feat, W_pins, b_pins, W_net, b_net,
      S_conn, S_pt, W_connect, b_connect, W_pt, b_pt, out);
}

// Round 8
// 283.555 us; speedup vs baseline: 1.7250x; 1.0719x over previous
//
#include <hip/hip_runtime.h>

typedef unsigned short u16;
typedef unsigned int u32;

#define NC 50000
#define NN 10000
#define NG 20000
#define NE 100000
#define NSCAN 150016   // 5 dst-count regions (150,000) padded
#define NBLK 74        // ceil(NSCAN / 2048)

// CSR dst regions inside hist/bases (element offsets):
// pins_dst    [0,      10000)   -> net rows    (gc payload)
// connect_dst [10000,  30000)   -> gcell rows  (gc payload)
// pt_dst      [30000,  50000)   -> gcell rows  (gc payload)
// pinned_dst  [50000, 100000)   -> cell rows   (nn payload, pos-300000)
// pf_dst      [100000,150000)   -> cell rows   (nn payload, pos-300000)

// ---------- bf16 helpers (workspace T tables only) ----------
__device__ __forceinline__ float bflo(u32 a) { return __uint_as_float(a << 16); }
__device__ __forceinline__ float bfhi(u32 a) { return __uint_as_float(a & 0xFFFF0000u); }
__device__ __forceinline__ u16 fbf(float f) {
  u32 u = __float_as_uint(f);
  return (u16)((u + 0x7FFFu + ((u >> 16) & 1u)) >> 16);  // RNE
}

// one NNConv edge message for lane-output o
__device__ __forceinline__ float nn_msg(int e, int s, const float* __restrict__ ef,
                                        const u16* __restrict__ T,
                                        const float* __restrict__ C, int o) {
  const float4* efp = reinterpret_cast<const float4*>(ef + (size_t)e * 16);
  float4 ea = efp[0], eb = efp[1], ec = efp[2], ed = efp[3];
  const uint4* tp = reinterpret_cast<const uint4*>(T + (size_t)s * 512 + o * 16);
  uint4 ta = tp[0], tb = tp[1];
  float m = C[(size_t)s * 32 + o];
  m += ea.x * bflo(ta.x) + ea.y * bfhi(ta.x) + ea.z * bflo(ta.y) + ea.w * bfhi(ta.y);
  m += eb.x * bflo(ta.z) + eb.y * bfhi(ta.z) + eb.z * bflo(ta.w) + eb.w * bfhi(ta.w);
  m += ec.x * bflo(tb.x) + ec.y * bfhi(tb.x) + ec.z * bflo(tb.y) + ec.w * bfhi(tb.y);
  m += ed.x * bflo(tb.z) + ed.y * bfhi(tb.z) + ed.z * bflo(tb.w) + ed.w * bfhi(tb.w);
  return m;
}

// ---------- K_FRONT: transform (469) | C (1875) | hist (196) ----------
// transform: register-blocked GEMM tile, 64 nodes/block, 2 j-outputs/thread.
//   LDS-staged h tile (one sync), w in 64 VGPRs, FMA-bound inner loop.
__global__ __launch_bounds__(512) void k_front(
    const float* __restrict__ feat_net, const float* __restrict__ feat_han,
    const float* __restrict__ W_topo, const float* __restrict__ b_topo,
    u16* __restrict__ T_net, u16* __restrict__ T_han,
    float* __restrict__ C_net, float* __restrict__ C_han,
    const int* __restrict__ pins_src, const int* __restrict__ pins_dst,
    const int* __restrict__ pinned_dst, const int* __restrict__ pf_dst,
    const int* __restrict__ connect_src, const int* __restrict__ connect_dst,
    const int* __restrict__ pt_src, const int* __restrict__ pt_dst,
    int* __restrict__ hist, int* __restrict__ srccnt) {
  int b = blockIdx.x;
  int tid = threadIdx.x;
  if (b < 469) {  // ---- transform: nodes [b*64, b*64+64) of 30000 ----
    __shared__ float hs[64][32];  // 8 KB
    int nd0 = b * 64;
    {  // stage: thread t loads float4 at element t*4 of the 64x32 tile
      int idx = tid * 4;
      int nl = idx >> 5, i = idx & 31;
      int ng = nd0 + nl;
      int ngc = min(ng, 29999);  // clamp (rows >= 30000 unused)
      const float* rp = (ngc < NN) ? feat_net + (size_t)ngc * 32
                                   : feat_han + (size_t)(ngc - NN) * 32;
      *reinterpret_cast<float4*>(&hs[nl][i]) =
          *reinterpret_cast<const float4*>(rp + i);
    }
    // w regs for j0 = 2*(tid&255), j1 = j0+1
    int jj = tid & 255;
    int j0 = jj * 2, j1 = j0 + 1;
    int p0 = j0 & 15, o0 = j0 >> 4;
    int p1 = j1 & 15, o1 = j1 >> 4;
    float w0[32], w1[32];
#pragma unroll
    for (int i = 0; i < 32; i++) {
      w0[i] = W_topo[p0 * 1024 + i * 32 + o0];
      w1[i] = W_topo[p1 * 1024 + i * 32 + o1];
    }
    __syncthreads();
    int g = tid >> 8;  // node half: 0 or 1 (wave-uniform)
#pragma unroll 4
    for (int n = 0; n < 32; n++) {
      int nl = g * 32 + n;
      float a0 = 0.f, a1 = 0.f;
#pragma unroll
      for (int i = 0; i < 32; i++) {
        float h = hs[nl][i];  // wave-uniform -> LDS broadcast
        a0 += h * w0[i];
        a1 += h * w1[i];
      }
      int s = nd0 + nl;
      if (s < 30000) {
        u32 pk = (u32)fbf(a0) | ((u32)fbf(a1) << 16);
        u32* dst = (s < NN)
            ? reinterpret_cast<u32*>(T_net + (size_t)s * 512 + j0)
            : reinterpret_cast<u32*>(T_han + (size_t)(s - NN) * 512 + j0);
        *dst = pk;
      }
    }
    return;
  }
  if (b < 2344) {  // ---- C: (NN+NG)*32 = 960,000 = 1875*512 exact ----
    int t = (b - 469) * 512 + tid;
    int s2 = t >> 5, o = t & 31;
    bool han = s2 >= NN;
    const float* feat = han ? feat_han : feat_net;
    float* C = han ? C_han : C_net;
    int s = han ? s2 - NN : s2;
    float acc = 0.f;
#pragma unroll 8
    for (int i = 0; i < 32; i++)
      acc += feat[(size_t)s * 32 + i] * b_topo[i * 32 + o];
    C[(size_t)s * 32 + o] = acc;
    return;
  }
  // ---- hist ----
  int e = (b - 2344) * 512 + tid;
  if (e >= NE) return;
  atomicAdd(&hist[pins_dst[e]], 1);
  atomicAdd(&hist[10000 + connect_dst[e]], 1);
  atomicAdd(&hist[30000 + pt_dst[e]], 1);
  atomicAdd(&hist[50000 + pinned_dst[e]], 1);
  atomicAdd(&hist[100000 + pf_dst[e]], 1);
  atomicAdd(&srccnt[pins_src[e]], 1);            // cell  [0,50000)
  atomicAdd(&srccnt[50000 + connect_src[e]], 1); // gcell [50000,70000)
  atomicAdd(&srccnt[70000 + pt_src[e]], 1);      // cell  [70000,120000)
}

// ---------- scan (2 kernels) ----------
__global__ __launch_bounds__(256) void k_scan1(
    const int* __restrict__ cnt, int* __restrict__ bsum) {
  __shared__ int sm[256];
  int b = blockIdx.x, tid = threadIdx.x;
  int base = b * 2048 + tid * 8;
  int tot = 0;
#pragma unroll
  for (int j = 0; j < 8; j++) {
    int i = base + j;
    tot += (i < NSCAN) ? cnt[i] : 0;
  }
  sm[tid] = tot;
  __syncthreads();
  for (int off = 128; off > 0; off >>= 1) {
    if (tid < off) sm[tid] += sm[tid + off];
    __syncthreads();
  }
  if (tid == 0) bsum[b] = sm[0];
}

__global__ __launch_bounds__(256) void k_scan3(
    const int* __restrict__ cnt, const int* __restrict__ bsum,
    int* __restrict__ bases) {
  __shared__ int sm[256];
  __shared__ int carry;
  int b = blockIdx.x, tid = threadIdx.x;
  if (tid == 0) {
    int run = 0;
    for (int i = 0; i < b; i++) run += bsum[i];
    carry = run;
  }
  int base = b * 2048 + tid * 8;
  int v[8];
  int tot = 0;
#pragma unroll
  for (int j = 0; j < 8; j++) {
    int i = base + j;
    v[j] = (i < NSCAN) ? cnt[i] : 0;
    tot += v[j];
  }
  sm[tid] = tot;
  __syncthreads();
  for (int off = 1; off < 256; off <<= 1) {
    int add = (tid >= off) ? sm[tid - off] : 0;
    __syncthreads();
    sm[tid] += add;
    __syncthreads();
  }
  int excl = sm[tid] - tot + carry;
#pragma unroll
  for (int j = 0; j < 8; j++) {
    int i = base + j;
    if (i < NSCAN) bases[i] = excl;
    excl += v[j];
  }
}

// ---------- K_FILL: payload CSRs ----------
// gc (rel 0..2): csr_gc[pos] = (src, bits(rsqrt(deg_src)))   -- 8B sequential payload
// nn (rel 3..4): csr_nn[pos-300000] = (e, src)
__global__ __launch_bounds__(512) void k_fill(
    const int* __restrict__ pins_src, const int* __restrict__ pins_dst,
    const int* __restrict__ connect_src, const int* __restrict__ connect_dst,
    const int* __restrict__ pt_src, const int* __restrict__ pt_dst,
    const int* __restrict__ pinned_src, const int* __restrict__ pinned_dst,
    const int* __restrict__ pf_src, const int* __restrict__ pf_dst,
    const int* __restrict__ srccnt,
    const int* __restrict__ bases, int* __restrict__ cursor,
    int2* __restrict__ csr_gc, int2* __restrict__ csr_nn) {
  int t = blockIdx.x * 512 + threadIdx.x;
  if (t >= 5 * NE) return;
  int r = (t >= NE) + (t >= 2 * NE) + (t >= 3 * NE) + (t >= 4 * NE);
  int e = t - r * NE;
  const int* srcs = r == 0 ? pins_src : r == 1 ? connect_src
                   : r == 2 ? pt_src : r == 3 ? pinned_src : pf_src;
  const int* dsts = r == 0 ? pins_dst : r == 1 ? connect_dst
                   : r == 2 ? pt_dst : r == 3 ? pinned_dst : pf_dst;
  int off = r == 0 ? 0 : r == 1 ? 10000 : r == 2 ? 30000 : r == 3 ? 50000 : 100000;
  int s = srcs[e];
  int g = off + dsts[e];
  int pos = atomicAdd(&cursor[g], 1);
  int cpos = bases[g] + pos;
  if (r < 3) {
    int soff = r == 0 ? 0 : r == 1 ? 50000 : 70000;
    float w = rsqrtf(fmaxf((float)srccnt[soff + s], 1.f));
    csr_gc[cpos] = make_int2(s, __float_as_int(w));
  } else {
    csr_nn[cpos - 300000] = make_int2(e, s);
  }
}

// ---------- K_GC: graph-conv gather (payload CSR: 1 random load/edge) ----------
__global__ __launch_bounds__(512) void k_gc_gather(
    const int* __restrict__ hist, const int* __restrict__ bases,
    const int2* __restrict__ csr_gc,
    const float* __restrict__ node_feat, const float* __restrict__ hanna_feat,
    float* __restrict__ S_net, float* __restrict__ S_conn, float* __restrict__ S_pt) {
  int t = blockIdx.x * 512 + threadIdx.x;  // 3125*512 = 1.6M exact
  int rr = t >> 5, o = t & 31;
  int rel = (rr >= 10000) + (rr >= 30000);
  const float* feat = (rel == 1) ? hanna_feat : node_feat;
  float* S = rel == 0 ? S_net + (size_t)rr * 32
           : rel == 1 ? S_conn + (size_t)(rr - 10000) * 32
                      : S_pt + (size_t)(rr - 30000) * 32;
  int base = bases[rr], deg = hist[rr];
  float acc = 0.f;
  int k = 0;
  for (; k + 1 < deg; k += 2) {
    int2 pa = csr_gc[base + k], pb = csr_gc[base + k + 1];
    acc += feat[(size_t)pa.x * 32 + o] * __int_as_float(pa.y) +
           feat[(size_t)pb.x * 32 + o] * __int_as_float(pb.y);
  }
  if (k < deg) {
    int2 pa = csr_gc[base + k];
    acc += feat[(size_t)pa.x * 32 + o] * __int_as_float(pa.y);
  }
  S[o] = acc;
}

// ---------- K_TAIL: nn_gather cells (3125) | net fin (625) | gcell fin (1250) ----------
__global__ __launch_bounds__(512) void k_tail(
    const int* __restrict__ hist, const int* __restrict__ bases,
    const int2* __restrict__ csr_nn,
    const float* __restrict__ pin_feat, const float* __restrict__ edge_feat,
    const u16* __restrict__ T_net, const u16* __restrict__ T_han,
    const float* __restrict__ C_net, const float* __restrict__ C_han,
    const float* __restrict__ b_pinned, const float* __restrict__ b_pf,
    const float* __restrict__ S_net, const float* __restrict__ net_feat,
    const float* __restrict__ W_pins, const float* __restrict__ b_pins,
    const float* __restrict__ W_net, const float* __restrict__ b_net,
    const float* __restrict__ S_conn, const float* __restrict__ S_pt,
    const float* __restrict__ W_connect, const float* __restrict__ b_connect,
    const float* __restrict__ W_pt, const float* __restrict__ b_pt,
    float* __restrict__ out) {
  __shared__ float Wa[1024], Wb[1024];
  int b = blockIdx.x;
  if (b < 3125) {  // ---- NNConv gather: NC*32 = 1.6M = 3125*512 exact ----
    int t = b * 512 + threadIdx.x;
    int d = t >> 5, o = t & 31;
    float a0 = 0.f, a1 = 0.f;
    {  // conv0: 'pinned' net -> cell
      int g = 50000 + d;
      int base = bases[g] - 300000, deg = hist[g];
      int k = 0;
      for (; k + 1 < deg; k += 2) {
        int2 ea = csr_nn[base + k], eb = csr_nn[base + k + 1];
        a0 += nn_msg(ea.x, ea.y, pin_feat, T_net, C_net, o) +
              nn_msg(eb.x, eb.y, pin_feat, T_net, C_net, o);
      }
      if (k < deg) {
        int2 ea = csr_nn[base + k];
        a0 += nn_msg(ea.x, ea.y, pin_feat, T_net, C_net, o);
      }
      a0 /= fmaxf((float)deg, 1.f);
    }
    {  // conv1: 'point-from' gcell -> cell
      int g = 100000 + d;
      int base = bases[g] - 300000, deg = hist[g];
      int k = 0;
      for (; k + 1 < deg; k += 2) {
        int2 ea = csr_nn[base + k], eb = csr_nn[base + k + 1];
        a1 += nn_msg(ea.x, ea.y, edge_feat, T_han, C_han, o) +
              nn_msg(eb.x, eb.y, edge_feat, T_han, C_han, o);
      }
      if (k < deg) {
        int2 ea = csr_nn[base + k];
        a1 += nn_msg(ea.x, ea.y, edge_feat, T_han, C_han, o);
      }
      a1 /= fmaxf((float)deg, 1.f);
    }
    out[(size_t)d * 32 + o] = a0 + a1 + b_pinned[o] + b_pf[o];
    return;
  }
  if (b < 3750) {  // ---- net fin: NN*32 = 320,000 = 625*512 exact ----
    for (int k = threadIdx.x; k < 1024; k += 512) {
      Wa[k] = W_pins[k];
      Wb[k] = W_net[k];
    }
    __syncthreads();
    int t = (b - 3125) * 512 + threadIdx.x;
    int r = t >> 5, o = t & 31;
    float a1 = 0.f, a2 = 0.f;
#pragma unroll 8
    for (int i = 0; i < 32; i++) {
      a1 += S_net[(size_t)r * 32 + i] * Wa[i * 32 + o];
      a2 += net_feat[(size_t)r * 32 + i] * Wb[i * 32 + o];
    }
    out[1600000 + t] = a1 * rsqrtf(fmaxf((float)hist[r], 1.f)) + b_pins[o] +
                       a2 + b_net[o];
    return;
  }
  // ---- gcell fin: NG*32 = 640,000 = 1250*512 exact ----
  for (int k = threadIdx.x; k < 1024; k += 512) {
    Wa[k] = W_connect[k];
    Wb[k] = W_pt[k];
  }
  __syncthreads();
  int t = (b - 3750) * 512 + threadIdx.x;
  int r = t >> 5, o = t & 31;
  float a1 = 0.f, a2 = 0.f;
#pragma unroll 8
  for (int i = 0; i < 32; i++) {
    a1 += S_conn[(size_t)r * 32 + i] * Wa[i * 32 + o];
    a2 += S_pt[(size_t)r * 32 + i] * Wb[i * 32 + o];
  }
  out[1920000 + t] = a1 * rsqrtf(fmaxf((float)hist[10000 + r], 1.f)) + b_connect[o] +
                     a2 * rsqrtf(fmaxf((float)hist[30000 + r], 1.f)) + b_pt[o];
}

extern "C" void kernel_launch(void* const* d_in, const int* in_sizes, int n_in,
                              void* d_out, int out_size, void* d_ws, size_t ws_size,
                              hipStream_t stream) {
  const float* node_feat  = (const float*)d_in[0];
  const float* net_feat   = (const float*)d_in[1];
  const float* pin_feat   = (const float*)d_in[2];
  const float* hanna_feat = (const float*)d_in[3];
  const float* edge_feat  = (const float*)d_in[4];
  const int* pins_src    = (const int*)d_in[5];
  const int* pins_dst    = (const int*)d_in[6];
  const int* pinned_src  = (const int*)d_in[7];
  const int* pinned_dst  = (const int*)d_in[8];
  const int* connect_src = (const int*)d_in[9];
  const int* connect_dst = (const int*)d_in[10];
  const int* pt_src      = (const int*)d_in[11];
  const int* pt_dst      = (const int*)d_in[12];
  const int* pf_src      = (const int*)d_in[13];
  const int* pf_dst      = (const int*)d_in[14];
  const float* W_net     = (const float*)d_in[15];
  const float* b_net     = (const float*)d_in[16];
  const float* W_topo    = (const float*)d_in[17];
  const float* b_topo    = (const float*)d_in[18];
  const float* W_pins    = (const float*)d_in[19];
  const float* b_pins    = (const float*)d_in[20];
  const float* W_connect = (const float*)d_in[21];
  const float* b_connect = (const float*)d_in[22];
  const float* W_pt      = (const float*)d_in[23];
  const float* b_pt      = (const float*)d_in[24];
  const float* b_pinned  = (const float*)d_in[25];
  const float* b_pf      = (const float*)d_in[26];
  float* out = (float*)d_out;

  // ---- workspace layout (47.24 MB total; < proven 48.44 MB) ----
  int* wi = (int*)d_ws;
  int* hist    = wi + 0;          // [0, 150016)
  int* cursor  = wi + 150016;     // [150016, 300032)
  int* srccnt  = wi + 300032;     // [300032, 420032)
  int* bases   = wi + 420032;     // [420032, 570064)
  int* bsum    = wi + 570064;     // [570064, 570192)
  int2* csr_gc = (int2*)(wi + 570192);   // 300,000 * 8B  -> int end 1,170,192
  int2* csr_nn = (int2*)(wi + 1170192);  // 200,000 * 8B  -> int end 1,570,192
  float* wf = (float*)d_ws;
  float* S_net  = wf + 1570192;   // NN*32
  float* S_conn = wf + 1890192;   // NG*32
  float* S_pt   = wf + 2530192;   // NG*32
  float* C_net  = wf + 3170192;   // NN*32
  float* C_han  = wf + 3490192;   // NG*32 -> float end 4,130,192 (byte 16,520,768)
  u16* T_net = (u16*)((char*)d_ws + 16520832);             // NN*512 bf16
  u16* T_han = (u16*)((char*)d_ws + 16520832 + 10240000);  // NG*512 bf16
  // end byte: 47,240,832

  hipMemsetAsync(d_ws, 0, 420032 * sizeof(int), stream);  // hist+cursor+srccnt

  k_front<<<2540, 512, 0, stream>>>(
      net_feat, hanna_feat, W_topo, b_topo, T_net, T_han, C_net, C_han,
      pins_src, pins_dst, pinned_dst, pf_dst, connect_src, connect_dst,
      pt_src, pt_dst, hist, srccnt);

  k_scan1<<<NBLK, 256, 0, stream>>>(hist, bsum);
  k_scan3<<<NBLK, 256, 0, stream>>>(hist, bsum, bases);

  k_fill<<<(5 * NE + 511) / 512, 512, 0, stream>>>(
      pins_src, pins_dst, connect_src, connect_dst, pt_src, pt_dst,
      pinned_src, pinned_dst, pf_src, pf_dst, srccnt, bases, cursor,
      csr_gc, csr_nn);

  k_gc_gather<<<3125, 512, 0, stream>>>(
      hist, bases, csr_gc, node_feat, hanna_feat, S_net, S_conn, S_pt);

  k_tail<<<5000, 512, 0, stream>>>(
      hist, bases, csr_nn, pin_feat, edge_feat,
      T_net, T_han, C_net, C_han, b_pinned, b_pf,
      S_net, net_feat, W_pins, b_pins, W_net, b_net,
      S_conn, S_pt, W_connect, b_connect, W_pt, b_pt, out);
}